// Round 27
// baseline (108.486 us; speedup 1.0000x reference)
//
#include <hip/hip_runtime.h>
#include <hip/hip_bf16.h>

// MultiheadAttention: out = (softmax_causal((Xq Wq^T)(Xk Wk^T)^T / 8) (Xv Wv^T)) Wo^T
// B=2 S=2048 D=1024 H=16 dk=64. bf16 MFMA (16x16x32), fp32 accum.
// R27: cvt's X round-trip (48MB rd + 24MB wr, ~11us) DELETED — proj_qkv
//      reads fp32 X directly: reg-stage 8xfloat4/thread/tile, convert, tail
//      ds_write (pre-swizzled) into As. B keeps gload_lds from bf16 weights.
//      Mixed vmcnt audited: top vmcnt(12) retires prior B-tile; writeA's reg
//      use drains A-loads to vmcnt(4); lgkm(0) publishes ds_writes. cvt now
//      weights-only (~4us). flash/proj_out = R26.

typedef __attribute__((ext_vector_type(8))) __bf16 bf16x8;
typedef __attribute__((ext_vector_type(4))) __bf16 bf16x4;
typedef __attribute__((ext_vector_type(4))) float f32x4;

#define MFMA16(a, b, c) __builtin_amdgcn_mfma_f32_16x16x32_bf16((a), (b), (c), 0, 0, 0)

constexpr int D_MODEL = 1024;
constexpr int HEADS   = 16;
constexpr int DKH     = 64;
constexpr int BATCH   = 2;
constexpr int SEQ     = 2048;
constexpr int M_ROWS  = BATCH * SEQ;  // 4096
constexpr int QB = 64, KB = 64, NT = SEQ / QB;  // 32 q-tiles

typedef const unsigned int __attribute__((address_space(1)))* gas_u32;
typedef unsigned int __attribute__((address_space(3)))* las_u32;

// ---------------------------------------------------------------------------
// fp32 -> bf16 convert, WEIGHTS ONLY: z=0 Wq (x0.125*log2e), z=1 Wk, z=2 Wv
// (granule-swizzled for gload_lds staging), z=3 Wo (linear, for proj_out).
// ---------------------------------------------------------------------------
struct CvtArgs {
  const float* src[4];
  __bf16* dst[4];
};

__global__ __launch_bounds__(256) void cvt_bf16(CvtArgs a) {
  const int z = blockIdx.z;
  const int i = blockIdx.x * 256 + threadIdx.x;   // granule id, < 131072
  const float sc = (z == 0) ? 0.18033688011112042f : 1.0f;  // 0.125*log2e
  const float4* s = (const float4*)a.src[z] + (size_t)i * 2;
  float4 x = s[0], y = s[1];
  bf16x8 o = {(__bf16)(x.x * sc), (__bf16)(x.y * sc), (__bf16)(x.z * sc), (__bf16)(x.w * sc),
              (__bf16)(y.x * sc), (__bf16)(y.y * sc), (__bf16)(y.z * sc), (__bf16)(y.w * sc)};
  size_t oi = (size_t)i;
  if (z < 3) {
    const int row = i >> 7;  // 1024 elems = 128 granules per row
    oi = (size_t)((i & ~7) | ((i & 7) ^ (row & 7)));
  }
  *(bf16x8*)(a.dst[z] + oi * 8) = o;
}

// ---------------------------------------------------------------------------
// proj_qkv FUSED: A = fp32 X (reg-staged + converted + tail ds_write,
// pre-swizzled), B = bf16 W via gload_lds. 128x128 tile, dbuf, grid 768
// (3 full CU rounds), XCD-pinned A panels. 4 waves 2x2, wave tile 64x64.
// ---------------------------------------------------------------------------
__global__ __launch_bounds__(256, 2) void proj_qkv(
    const float* __restrict__ Xq, const float* __restrict__ Xk,
    const float* __restrict__ Xv, const __bf16* __restrict__ Wq,
    const __bf16* __restrict__ Wk, const __bf16* __restrict__ Wv,
    __bf16* __restrict__ Q, __bf16* __restrict__ K, __bf16* __restrict__ Vt) {
  __shared__ alignas(16) __bf16 As[2][128 * 64];  // 32 KB
  __shared__ alignas(16) __bf16 Bs[2][128 * 64];  // 32 KB

  const int f = blockIdx.x;
  const int x = f & 7, w = f >> 3;
  const int bz = w >> 5, rem = w & 31;
  const int by = x * 4 + (rem & 3);
  const int bx = rem >> 2;

  const float* Ag; const __bf16* Bg;
  if (bz == 0)      { Ag = Xq; Bg = Wq; }
  else if (bz == 1) { Ag = Xk; Bg = Wk; }
  else              { Ag = Xv; Bg = Wv; }

  const int bm = by * 128, bn = bx * 128;
  const int tid = threadIdx.x, ln = tid & 63, wv = tid >> 6;
  const int wr = wv >> 1, wc = wv & 1;       // 2x2 wave grid, 64x64 tile
  const int fr = ln & 15, fg = ln >> 4;

  // A fp32 staging: 1024 granules (8 elems); thread owns granules
  // {tid, tid+256, tid+512, tid+768} -> row=(tid>>3)+32j, g=tid&7 (coalesced)
  float4 av[8];
  const int arow0 = tid >> 3, ag = tid & 7;
  const int agsw  = ag ^ (arow0 & 7);    // (row&7) same for all j (32j%8==0)

  auto loadAreg = [&](int t) {
    const int kt = t * 64;
#pragma unroll
    for (int j = 0; j < 4; ++j) {
      const float* src = Ag + (size_t)(bm + arow0 + j * 32) * 1024 + kt + ag * 8;
      av[2 * j]     = *(const float4*)src;
      av[2 * j + 1] = *(const float4*)(src + 4);
    }
  };
  auto writeA = [&](int buf) {
#pragma unroll
    for (int j = 0; j < 4; ++j) {
      bf16x8 o = {(__bf16)av[2 * j].x,     (__bf16)av[2 * j].y,
                  (__bf16)av[2 * j].z,     (__bf16)av[2 * j].w,
                  (__bf16)av[2 * j + 1].x, (__bf16)av[2 * j + 1].y,
                  (__bf16)av[2 * j + 1].z, (__bf16)av[2 * j + 1].w};
      *(bf16x8*)&As[buf][(arow0 + j * 32) * 64 + agsw * 8] = o;
    }
  };
  auto stageB = [&](int buf, int t) {
    const int kt = t * 64;
#pragma unroll
    for (int i = 0; i < 4; ++i) {
      const int c = wv * 4 + i;
      const int byte = c * 1024 + ln * 16;
      const int row = byte >> 7;
      const int col = (byte & 127) >> 1;
      const __bf16* gb = Bg + (size_t)(bn + row) * 1024 + kt + col;
      __builtin_amdgcn_global_load_lds((gas_u32)gb, (las_u32)(&Bs[buf][c * 512]),
                                       16, 0, 0);
    }
  };

  f32x4 acc[4][4];
#pragma unroll
  for (int m = 0; m < 4; ++m)
#pragma unroll
    for (int n = 0; n < 4; ++n) acc[m][n] = (f32x4){0.f, 0.f, 0.f, 0.f};

  // prologue: tile 0 (A regs -> LDS now; B via gload)
  loadAreg(0);
  stageB(0, 0);
  writeA(0);
  asm volatile("s_waitcnt vmcnt(0) lgkmcnt(0)" ::: "memory");
  __builtin_amdgcn_s_barrier();

#pragma unroll 1
  for (int t = 0; t < 16; ++t) {
    const int cur = t & 1;
    // top: issue tile t+1 (A regs + B gloads); vmcnt(12) retires B(t)
    // [outstanding after issue: B(t) 4 + A(t+1) 8 + B(t+1) 4 = 16 max]
    if (t + 1 < 16) {
      loadAreg(t + 1);
      stageB(cur ^ 1, t + 1);
      asm volatile("s_waitcnt vmcnt(12)" ::: "memory");
    } else {
      asm volatile("s_waitcnt vmcnt(0)" ::: "memory");
    }
    __builtin_amdgcn_s_barrier();  // B(t) in LDS (each wave drained); A(t)
                                   // ds_writes published (lgkm drained below)

#pragma unroll
    for (int kk = 0; kk < 2; ++kk) {
      bf16x8 af[4], bfv[4];
#pragma unroll
      for (int m = 0; m < 4; ++m) {
        const int row = wr * 64 + m * 16 + fr;
        af[m] = *(const bf16x8*)&As[cur][row * 64 + (((kk * 4 + fg) ^ (row & 7)) << 3)];
      }
#pragma unroll
      for (int n = 0; n < 4; ++n) {
        const int row = wc * 64 + n * 16 + fr;
        bfv[n] = *(const bf16x8*)&Bs[cur][row * 64 + (((kk * 4 + fg) ^ (row & 7)) << 3)];
      }
      __builtin_amdgcn_s_setprio(1);
#pragma unroll
      for (int m = 0; m < 4; ++m)
#pragma unroll
        for (int n = 0; n < 4; ++n) acc[m][n] = MFMA16(af[m], bfv[n], acc[m][n]);
      __builtin_amdgcn_s_setprio(0);
    }
    __builtin_amdgcn_s_barrier();  // reads of As/Bs[cur] done before overwrite

    // tail: convert + ds_write A(t+1) into As[cur^1] (readers finished two
    // barriers ago); lgkm drain publishes before next top barrier.
    if (t + 1 < 16) {
      writeA(cur ^ 1);
      asm volatile("s_waitcnt lgkmcnt(0)" ::: "memory");
    }
  }

  if (bz == 2) {
    const int b = bm >> 11;
#pragma unroll
    for (int m = 0; m < 4; ++m)
#pragma unroll
      for (int n = 0; n < 4; ++n) {
        const int col = bn + wc * 64 + n * 16 + fr;
        const int s0  = (bm + wr * 64 + m * 16 + fg * 4) & (SEQ - 1);
        bf16x4 o = {(__bf16)acc[m][n][0], (__bf16)acc[m][n][1],
                    (__bf16)acc[m][n][2], (__bf16)acc[m][n][3]};
        *(bf16x4*)(Vt + (((size_t)(b * 1024 + col)) << 11) + s0) = o;
      }
  } else {
    __bf16* C = (bz == 0) ? Q : K;
#pragma unroll
    for (int m = 0; m < 4; ++m)
#pragma unroll
      for (int n = 0; n < 4; ++n)
#pragma unroll
        for (int r = 0; r < 4; ++r) {
          const int row = bm + wr * 64 + m * 16 + fg * 4 + r;
          const int col = bn + wc * 64 + n * 16 + fr;
          C[(size_t)row * 1024 + col] = (__bf16)acc[m][n][r];
        }
  }
}

// ---------------------------------------------------------------------------
// proj_out: 128x64 tile, double-buffered, counted vmcnt(6), XCD-pinned map
// (R25, unchanged).
// ---------------------------------------------------------------------------
__global__ __launch_bounds__(256) void proj_out(const __bf16* __restrict__ Aattn,
                                                const __bf16* __restrict__ Wo,
                                                float* __restrict__ Out) {
  __shared__ alignas(16) __bf16 As[2][128 * 64];  // 32 KB
  __shared__ alignas(16) __bf16 Bs[2][64 * 64];   // 16 KB

  const int f = blockIdx.x;             // 0..511
  const int x = f & 7, w = f >> 3;
  const int by = x * 4 + (w & 3);       // 0..31
  const int bx = w >> 2;                // 0..15
  const int bm = by * 128, bn = bx * 64;

  const int tid = threadIdx.x, ln = tid & 63, wv = tid >> 6;
  const int wr = wv >> 1, wc = wv & 1;
  const int fr = ln & 15, fg = ln >> 4;

  auto stage = [&](int buf, int t) {
    const int kt = t * 64;
#pragma unroll
    for (int i = 0; i < 4; ++i) {  // A: 16 chunks of 1KB
      const int c = wv * 4 + i;
      const int byte = c * 1024 + ln * 16;
      const int row = byte >> 7;
      const int col = (byte & 127) >> 1;
      const __bf16* ga = Aattn + (size_t)(bm + row) * 1024 + kt + col;
      __builtin_amdgcn_global_load_lds((gas_u32)ga, (las_u32)(&As[buf][c * 512]),
                                       16, 0, 0);
    }
#pragma unroll
    for (int i = 0; i < 2; ++i) {  // B: 8 chunks of 1KB
      const int c = wv * 2 + i;
      const int byte = c * 1024 + ln * 16;
      const int row = byte >> 7;
      const int col = (byte & 127) >> 1;
      const __bf16* gb = Wo + (size_t)(bn + row) * 1024 + kt + col;
      __builtin_amdgcn_global_load_lds((gas_u32)gb, (las_u32)(&Bs[buf][c * 512]),
                                       16, 0, 0);
    }
  };

  f32x4 acc[4][2];
#pragma unroll
  for (int m = 0; m < 4; ++m)
#pragma unroll
    for (int n = 0; n < 2; ++n) acc[m][n] = (f32x4){0.f, 0.f, 0.f, 0.f};

  stage(0, 0);

#pragma unroll 1
  for (int t = 0; t < 16; ++t) {
    const int cur = t & 1;
    if (t + 1 < 16) {
      stage(cur ^ 1, t + 1);
      asm volatile("s_waitcnt vmcnt(6)" ::: "memory");  // tile t landed
    } else {
      asm volatile("s_waitcnt vmcnt(0)" ::: "memory");
    }
    __builtin_amdgcn_s_barrier();

#pragma unroll
    for (int kk = 0; kk < 2; ++kk) {
      const int kc = kk * 32 + fg * 8;
      bf16x8 af[4], bfv[2];
#pragma unroll
      for (int m = 0; m < 4; ++m)
        af[m] = *(const bf16x8*)&As[cur][(wr * 64 + m * 16 + fr) * 64 + kc];
#pragma unroll
      for (int n = 0; n < 2; ++n)
        bfv[n] = *(const bf16x8*)&Bs[cur][(wc * 32 + n * 16 + fr) * 64 + kc];
#pragma unroll
      for (int m = 0; m < 4; ++m)
#pragma unroll
        for (int n = 0; n < 2; ++n) acc[m][n] = MFMA16(af[m], bfv[n], acc[m][n]);
    }
    __builtin_amdgcn_s_barrier();
  }

#pragma unroll
  for (int m = 0; m < 4; ++m)
#pragma unroll
    for (int n = 0; n < 2; ++n)
#pragma unroll
      for (int r = 0; r < 4; ++r) {
        const int row = bm + wr * 64 + m * 16 + fg * 4 + r;
        const int col = bn + wc * 32 + n * 16 + fr;
        Out[(size_t)row * 1024 + col] = acc[m][n][r];
      }
}

// ---------------------------------------------------------------------------
// Flash attention, causal, KV-split + XCD pinning (R24, unchanged).
// ---------------------------------------------------------------------------
__device__ __forceinline__ int SWZ(int row, int col) {
  return row * 64 + (col ^ ((row & 7) << 3));
}

__global__ __launch_bounds__(512, 2) void flash_attn(
    const __bf16* __restrict__ Q, const __bf16* __restrict__ K,
    const __bf16* __restrict__ Vt, __bf16* __restrict__ O) {
  __shared__ alignas(16) __bf16 Ks[2][2][64 * 64];  // [grp][buf] 32 KB
  __shared__ alignas(16) __bf16 Vs[2][2][64 * 64];  // 32 KB
  __shared__ alignas(16) __bf16 Ps[8][16 * 64];     // 16 KB (reused: merge acc)

  const int f  = blockIdx.x;            // 0..1023
  const int x  = f & 7, w = f >> 3;     // w 0..127
  const int qt = 31 - (w >> 2);         // longest first
  const int bh = x * 4 + (w & 3);
  const int b  = bh >> 4;
  const int h  = bh & 15;

  const int tid  = threadIdx.x;
  const int lane = tid & 63, wave = tid >> 6;
  const int grp = wave >> 2, wg = wave & 3;  // group / wave-in-group
  const int fr = lane & 15, fg = lane >> 4;

  const int len = qt + 1;
  const int h0  = (len + 1) >> 1;       // grp0 [0,h0), grp1 [h0,len)
  const int t0  = grp ? h0 : 0;
  const int tlast = grp ? len : h0;     // exclusive end of this grp's range

  const __bf16* Kh = K + (size_t)b * SEQ * D_MODEL + h * DKH;
  const __bf16* Vh = Vt + (size_t)(bh * DKH) * SEQ;

  auto stage = [&](int buf, int t) {
#pragma unroll
    for (int p = 0; p < 2; ++p) {
      const int row = p * 32 + wg * 8 + (lane >> 3);
      const int sg  = (lane & 7) ^ (row & 7);
      const __bf16* ks = Kh + (size_t)(t * KB + row) * D_MODEL + sg * 8;
      __builtin_amdgcn_global_load_lds((gas_u32)ks,
          (las_u32)(&Ks[grp][buf][(size_t)(p * 256 + wg * 64) * 8]), 16, 0, 0);
      const __bf16* vs = Vh + (size_t)row * SEQ + t * KB + sg * 8;
      __builtin_amdgcn_global_load_lds((gas_u32)vs,
          (las_u32)(&Vs[grp][buf][(size_t)(p * 256 + wg * 64) * 8]), 16, 0, 0);
    }
  };

  f32x4 acc[4];
#pragma unroll
  for (int n = 0; n < 4; ++n) acc[n] = (f32x4){0.f, 0.f, 0.f, 0.f};
  f32x4 l4 = (f32x4){0.f, 0.f, 0.f, 0.f};

  bf16x8 q0, q1;
  {
    const size_t qrow = (size_t)(b * SEQ + qt * QB + wg * 16 + fr) * D_MODEL + h * DKH;
    q0 = *(const bf16x8*)(Q + qrow + fg * 8);
    q1 = *(const bf16x8*)(Q + qrow + 32 + fg * 8);
  }

  const bf16x8 ones = {(__bf16)1.f, (__bf16)1.f, (__bf16)1.f, (__bf16)1.f,
                       (__bf16)1.f, (__bf16)1.f, (__bf16)1.f, (__bf16)1.f};

  auto step = [&](const int t, const int cur, __bf16* __restrict__ ps) {
    f32x4 s[4];
    __builtin_amdgcn_s_setprio(1);
#pragma unroll
    for (int kb = 0; kb < 4; ++kb) {
      f32x4 a = (f32x4){0.f, 0.f, 0.f, 0.f};
      bf16x8 kf0 = *(const bf16x8*)&Ks[grp][cur][SWZ(kb * 16 + fr, fg * 8)];
      bf16x8 kf1 = *(const bf16x8*)&Ks[grp][cur][SWZ(kb * 16 + fr, 32 + fg * 8)];
      a = MFMA16(kf0, q0, a);
      a = MFMA16(kf1, q1, a);
      s[kb] = a;
    }
    __builtin_amdgcn_s_setprio(0);

    if (t == qt) {  // causal mask, lane-local (diagonal KV tile)
      const int qin = wg * 16 + fr;
#pragma unroll
      for (int kb = 0; kb < 4; ++kb)
#pragma unroll
        for (int r = 0; r < 4; ++r)
          if (kb * 16 + fg * 4 + r > qin) s[kb][r] = -INFINITY;
    }

#pragma unroll
    for (int kb = 0; kb < 4; ++kb) {
      bf16x4 wv = {(__bf16)__builtin_amdgcn_exp2f(s[kb][0]),
                   (__bf16)__builtin_amdgcn_exp2f(s[kb][1]),
                   (__bf16)__builtin_amdgcn_exp2f(s[kb][2]),
                   (__bf16)__builtin_amdgcn_exp2f(s[kb][3])};
      *(bf16x4*)&ps[SWZ(fr, kb * 16 + fg * 4)] = wv;
    }

    __builtin_amdgcn_s_setprio(1);
#pragma unroll
    for (int k2 = 0; k2 < 2; ++k2) {
      bf16x8 pf = *(const bf16x8*)&ps[SWZ(fr, k2 * 32 + fg * 8)];
#pragma unroll
      for (int n = 0; n < 4; ++n) {
        bf16x8 vf = *(const bf16x8*)&Vs[grp][cur][SWZ(n * 16 + fr, k2 * 32 + fg * 8)];
        acc[n] = MFMA16(pf, vf, acc[n]);
      }
      l4 = MFMA16(pf, ones, l4);
    }
    __builtin_amdgcn_s_setprio(0);
  };

  stage(0, t0);
  asm volatile("s_waitcnt vmcnt(0)" ::: "memory");
  __syncthreads();

#pragma unroll 1
  for (int i = 0; i < h0; ++i) {
    const int t = t0 + i;
    const int cur = i & 1;

    if (t + 1 < tlast) stage(cur ^ 1, t + 1);  // latency hides under step
    if (t < tlast) step(t, cur, &Ps[wave][0]);

    asm volatile("s_waitcnt vmcnt(0)" ::: "memory");
    __syncthreads();
  }

  // ---- merge (m=0): O = (acc0 + acc1) / (l0 + l1) ----
  float* accb = (float*)&Ps[0][0];        // 4 waves x 16 x 64 f32 = 16 KB
  float* lb   = (float*)&Ks[0][0][0];     // 4 KB scratch (grp0 buf0, done)
  if (grp == 1) {
#pragma unroll
    for (int n = 0; n < 4; ++n)
#pragma unroll
      for (int r = 0; r < 4; ++r)
        accb[(wg * 16 + n * 4 + r) * 64 + lane] = acc[n][r];
#pragma unroll
    for (int r = 0; r < 4; ++r) lb[(wg * 4 + r) * 64 + lane] = l4[r];
  }
  __syncthreads();
  if (grp == 0) {
#pragma unroll
    for (int n = 0; n < 4; ++n)
#pragma unroll
      for (int r = 0; r < 4; ++r) acc[n][r] += accb[(wg * 16 + n * 4 + r) * 64 + lane];
#pragma unroll
    for (int r = 0; r < 4; ++r) l4[r] += lb[(wg * 4 + r) * 64 + lane];

    const size_t obase = (size_t)(b * SEQ + qt * QB + wg * 16) * D_MODEL + h * DKH;
#pragma unroll
    for (int n = 0; n < 4; ++n)
#pragma unroll
      for (int r = 0; r < 4; ++r) {
        const int row = fg * 4 + r;
        O[obase + (size_t)row * D_MODEL + n * 16 + fr] =
            (__bf16)(acc[n][r] / l4[r]);
      }
  }
}

// ---------------------------------------------------------------------------
extern "C" void kernel_launch(void* const* d_in, const int* in_sizes, int n_in,
                              void* d_out, int out_size, void* d_ws, size_t ws_size,
                              hipStream_t stream) {
  const float* q_src = (const float*)d_in[0];
  const float* k_src = (const float*)d_in[1];
  const float* v_src = (const float*)d_in[2];
  // d_in[3] = causal tril mask (fixed) -> applied analytically
  const float* Wq = (const float*)d_in[4];
  const float* Wk = (const float*)d_in[5];
  const float* Wv = (const float*)d_in[6];
  const float* Wo = (const float*)d_in[7];

  const size_t NE = (size_t)M_ROWS * D_MODEL;  // 4M elems
  const size_t NW = (size_t)D_MODEL * D_MODEL; // 1M elems
  __bf16* Wqb = (__bf16*)d_ws;
  __bf16* Wkb = Wqb + NW;
  __bf16* Wvb = Wkb + NW;
  __bf16* Wob = Wvb + NW;
  __bf16* Q   = Wob + NW;
  __bf16* K   = Q + NE;
  __bf16* Vt  = K + NE;
  __bf16* A   = Vt + NE;

  CvtArgs ca;
  ca.src[0] = Wq; ca.dst[0] = Wqb;  // x0.125*log2e, swizzled
  ca.src[1] = Wk; ca.dst[1] = Wkb;  // swizzled
  ca.src[2] = Wv; ca.dst[2] = Wvb;  // swizzled
  ca.src[3] = Wo; ca.dst[3] = Wob;  // linear

  cvt_bf16<<<dim3((unsigned)(NW / 8 / 256), 1, 4), dim3(256), 0, stream>>>(ca);
  proj_qkv<<<dim3(768), dim3(256), 0, stream>>>(
      q_src, k_src, v_src, Wqb, Wkb, Wvb, Q, K, Vt);
  flash_attn<<<dim3(NT * BATCH * HEADS), dim3(512), 0, stream>>>(Q, K, Vt, A);
  proj_out<<<dim3(512), dim3(256), 0, stream>>>(A, Wob, (float*)d_out);
}

// Round 28
// 106.254 us; speedup vs baseline: 1.0210x; 1.0210x over previous
//
#include <hip/hip_runtime.h>
#include <hip/hip_bf16.h>

// MultiheadAttention: out = (softmax_causal((Xq Wq^T)(Xk Wk^T)^T / 8) (Xv Wv^T)) Wo^T
// B=2 S=2048 D=1024 H=16 dk=64. bf16 MFMA (16x16x32), fp32 accum.
// R28: pure revert to R26 (measured best, 106.0us). R27's cvt-fusion into
//      proj_qkv was falsified: fp32 X re-read 8x per column-block (+12MB
//      FETCH) + per-thread ds_write staging cost >> the 11us cvt saving.
//      Final configuration: pre-convert (BW floor) + 128^2 dbuf proj_qkv +
//      KV-split XCD-pinned flash + dbuf proj_out.

typedef __attribute__((ext_vector_type(8))) __bf16 bf16x8;
typedef __attribute__((ext_vector_type(4))) __bf16 bf16x4;
typedef __attribute__((ext_vector_type(4))) float f32x4;

#define MFMA16(a, b, c) __builtin_amdgcn_mfma_f32_16x16x32_bf16((a), (b), (c), 0, 0, 0)

constexpr int D_MODEL = 1024;
constexpr int HEADS   = 16;
constexpr int DKH     = 64;
constexpr int BATCH   = 2;
constexpr int SEQ     = 2048;
constexpr int M_ROWS  = BATCH * SEQ;  // 4096
constexpr int QB = 64, KB = 64, NT = SEQ / QB;  // 32 q-tiles

typedef const unsigned int __attribute__((address_space(1)))* gas_u32;
typedef unsigned int __attribute__((address_space(3)))* las_u32;

// ---------------------------------------------------------------------------
// fp32 -> bf16 convert; seg 3 (Wq) pre-scaled by 0.125*log2(e) (exp2 softmax).
// Segs 0-5 granule-swizzled for the GEMM staging (rule #21).
// ---------------------------------------------------------------------------
struct CvtArgs {
  const float* src[7];
  __bf16* dst[7];
  int n8[7];
};

__global__ __launch_bounds__(256) void cvt_bf16(CvtArgs a) {
  const int z = blockIdx.z;
  const int i = blockIdx.x * 256 + threadIdx.x;
  if (i >= a.n8[z]) return;
  const float sc = (z == 3) ? 0.18033688011112042f : 1.0f;  // 0.125*log2e
  const float4* s = (const float4*)a.src[z] + (size_t)i * 2;
  float4 x = s[0], y = s[1];
  bf16x8 o = {(__bf16)(x.x * sc), (__bf16)(x.y * sc), (__bf16)(x.z * sc), (__bf16)(x.w * sc),
              (__bf16)(y.x * sc), (__bf16)(y.y * sc), (__bf16)(y.z * sc), (__bf16)(y.w * sc)};
  size_t oi = (size_t)i;
  if (z < 6) {
    const int row = i >> 7;  // 1024 elems = 128 granules per row
    oi = (size_t)((i & ~7) | ((i & 7) ^ (row & 7)));
  }
  *(bf16x8*)(a.dst[z] + oi * 8) = o;
}

// ---------------------------------------------------------------------------
// proj_qkv: 128x128 tile, double-buffered, counted vmcnt(8). Grid 768
// (= 3 full rounds of 256 CUs). 4 waves 2x2, wave tile 64x64, acc[4][4].
// XCD map: x = f&7 owns A row-panels {4x..4x+3} per z.
// ---------------------------------------------------------------------------
__global__ __launch_bounds__(256) void proj_qkv(
    const __bf16* __restrict__ Xq, const __bf16* __restrict__ Xk,
    const __bf16* __restrict__ Xv, const __bf16* __restrict__ Wq,
    const __bf16* __restrict__ Wk, const __bf16* __restrict__ Wv,
    __bf16* __restrict__ Q, __bf16* __restrict__ K, __bf16* __restrict__ Vt) {
  __shared__ alignas(16) __bf16 As[2][128 * 64];  // 32 KB
  __shared__ alignas(16) __bf16 Bs[2][128 * 64];  // 32 KB

  // f = 0..767; x = f&7 (dispatch XCD); w = f>>3 (0..95):
  // bz = w/32, rem = w%32, by = x*4 + (rem&3) (0..31), bx = rem>>2 (0..7)
  const int f = blockIdx.x;
  const int x = f & 7, w = f >> 3;
  const int bz = w >> 5, rem = w & 31;
  const int by = x * 4 + (rem & 3);
  const int bx = rem >> 2;

  const __bf16* Ag; const __bf16* Bg;
  if (bz == 0)      { Ag = Xq; Bg = Wq; }
  else if (bz == 1) { Ag = Xk; Bg = Wk; }
  else              { Ag = Xv; Bg = Wv; }

  const int bm = by * 128, bn = bx * 128;
  const int tid = threadIdx.x, ln = tid & 63, wv = tid >> 6;
  const int wr = wv >> 1, wc = wv & 1;       // 2x2 wave grid, 64x64 tile
  const int fr = ln & 15, fg = ln >> 4;

  // stage one 128x64 A-tile + 128x64 B-tile (16 chunks of 1KB each);
  // 4 chunks/wave each -> 8 global_load_lds per thread per tile.
  auto stage = [&](int buf, int t) {
    const int kt = t * 64;
#pragma unroll
    for (int i = 0; i < 4; ++i) {
      const int c = wv * 4 + i;
      const int byte = c * 1024 + ln * 16;
      const int row = byte >> 7;
      const int col = (byte & 127) >> 1;
      const __bf16* ga = Ag + (size_t)(bm + row) * 1024 + kt + col;
      __builtin_amdgcn_global_load_lds((gas_u32)ga, (las_u32)(&As[buf][c * 512]),
                                       16, 0, 0);
      const __bf16* gb = Bg + (size_t)(bn + row) * 1024 + kt + col;
      __builtin_amdgcn_global_load_lds((gas_u32)gb, (las_u32)(&Bs[buf][c * 512]),
                                       16, 0, 0);
    }
  };

  f32x4 acc[4][4];
#pragma unroll
  for (int m = 0; m < 4; ++m)
#pragma unroll
    for (int n = 0; n < 4; ++n) acc[m][n] = (f32x4){0.f, 0.f, 0.f, 0.f};

  stage(0, 0);

#pragma unroll 1
  for (int t = 0; t < 16; ++t) {
    const int cur = t & 1;
    // stage t+1 into buf cur^1 (readers finished at iter t-1's trailing
    // barrier); newest 8 outstanding = tile t+1 -> vmcnt(8) proves t landed.
    if (t + 1 < 16) {
      stage(cur ^ 1, t + 1);
      asm volatile("s_waitcnt vmcnt(8)" ::: "memory");
    } else {
      asm volatile("s_waitcnt vmcnt(0)" ::: "memory");
    }
    __builtin_amdgcn_s_barrier();

#pragma unroll
    for (int kk = 0; kk < 2; ++kk) {
      bf16x8 af[4], bfv[4];
#pragma unroll
      for (int m = 0; m < 4; ++m) {
        const int row = wr * 64 + m * 16 + fr;
        af[m] = *(const bf16x8*)&As[cur][row * 64 + (((kk * 4 + fg) ^ (row & 7)) << 3)];
      }
#pragma unroll
      for (int n = 0; n < 4; ++n) {
        const int row = wc * 64 + n * 16 + fr;
        bfv[n] = *(const bf16x8*)&Bs[cur][row * 64 + (((kk * 4 + fg) ^ (row & 7)) << 3)];
      }
      __builtin_amdgcn_s_setprio(1);
#pragma unroll
      for (int m = 0; m < 4; ++m)
#pragma unroll
        for (int n = 0; n < 4; ++n) acc[m][n] = MFMA16(af[m], bfv[n], acc[m][n]);
      __builtin_amdgcn_s_setprio(0);
    }
    __builtin_amdgcn_s_barrier();  // protect buf cur from next iter's stage
  }

  if (bz == 2) {
    // Vt[(b*1024 + col)][s]: per frag 4 contiguous s at fixed col
    const int b = bm >> 11;
#pragma unroll
    for (int m = 0; m < 4; ++m)
#pragma unroll
      for (int n = 0; n < 4; ++n) {
        const int col = bn + wc * 64 + n * 16 + fr;
        const int s0  = (bm + wr * 64 + m * 16 + fg * 4) & (SEQ - 1);
        bf16x4 o = {(__bf16)acc[m][n][0], (__bf16)acc[m][n][1],
                    (__bf16)acc[m][n][2], (__bf16)acc[m][n][3]};
        *(bf16x4*)(Vt + (((size_t)(b * 1024 + col)) << 11) + s0) = o;
      }
  } else {
    __bf16* C = (bz == 0) ? Q : K;
#pragma unroll
    for (int m = 0; m < 4; ++m)
#pragma unroll
      for (int n = 0; n < 4; ++n)
#pragma unroll
        for (int r = 0; r < 4; ++r) {
          const int row = bm + wr * 64 + m * 16 + fg * 4 + r;
          const int col = bn + wc * 64 + n * 16 + fr;
          C[(size_t)row * 1024 + col] = (__bf16)acc[m][n][r];
        }
  }
}

// ---------------------------------------------------------------------------
// proj_out: 128x64 tile, double-buffered, counted vmcnt(6), XCD-pinned map
// (R25, unchanged).
// ---------------------------------------------------------------------------
__global__ __launch_bounds__(256) void proj_out(const __bf16* __restrict__ Aattn,
                                                const __bf16* __restrict__ Wo,
                                                float* __restrict__ Out) {
  __shared__ alignas(16) __bf16 As[2][128 * 64];  // 32 KB
  __shared__ alignas(16) __bf16 Bs[2][64 * 64];   // 16 KB

  const int f = blockIdx.x;             // 0..511
  const int x = f & 7, w = f >> 3;
  const int by = x * 4 + (w & 3);       // 0..31
  const int bx = w >> 2;                // 0..15
  const int bm = by * 128, bn = bx * 64;

  const int tid = threadIdx.x, ln = tid & 63, wv = tid >> 6;
  const int wr = wv >> 1, wc = wv & 1;
  const int fr = ln & 15, fg = ln >> 4;

  auto stage = [&](int buf, int t) {
    const int kt = t * 64;
#pragma unroll
    for (int i = 0; i < 4; ++i) {  // A: 16 chunks of 1KB
      const int c = wv * 4 + i;
      const int byte = c * 1024 + ln * 16;
      const int row = byte >> 7;
      const int col = (byte & 127) >> 1;
      const __bf16* ga = Aattn + (size_t)(bm + row) * 1024 + kt + col;
      __builtin_amdgcn_global_load_lds((gas_u32)ga, (las_u32)(&As[buf][c * 512]),
                                       16, 0, 0);
    }
#pragma unroll
    for (int i = 0; i < 2; ++i) {  // B: 8 chunks of 1KB
      const int c = wv * 2 + i;
      const int byte = c * 1024 + ln * 16;
      const int row = byte >> 7;
      const int col = (byte & 127) >> 1;
      const __bf16* gb = Wo + (size_t)(bn + row) * 1024 + kt + col;
      __builtin_amdgcn_global_load_lds((gas_u32)gb, (las_u32)(&Bs[buf][c * 512]),
                                       16, 0, 0);
    }
  };

  f32x4 acc[4][2];
#pragma unroll
  for (int m = 0; m < 4; ++m)
#pragma unroll
    for (int n = 0; n < 2; ++n) acc[m][n] = (f32x4){0.f, 0.f, 0.f, 0.f};

  stage(0, 0);

#pragma unroll 1
  for (int t = 0; t < 16; ++t) {
    const int cur = t & 1;
    if (t + 1 < 16) {
      stage(cur ^ 1, t + 1);
      asm volatile("s_waitcnt vmcnt(6)" ::: "memory");  // tile t landed
    } else {
      asm volatile("s_waitcnt vmcnt(0)" ::: "memory");
    }
    __builtin_amdgcn_s_barrier();

#pragma unroll
    for (int kk = 0; kk < 2; ++kk) {
      const int kc = kk * 32 + fg * 8;
      bf16x8 af[4], bfv[2];
#pragma unroll
      for (int m = 0; m < 4; ++m)
        af[m] = *(const bf16x8*)&As[cur][(wr * 64 + m * 16 + fr) * 64 + kc];
#pragma unroll
      for (int n = 0; n < 2; ++n)
        bfv[n] = *(const bf16x8*)&Bs[cur][(wc * 32 + n * 16 + fr) * 64 + kc];
#pragma unroll
      for (int m = 0; m < 4; ++m)
#pragma unroll
        for (int n = 0; n < 2; ++n) acc[m][n] = MFMA16(af[m], bfv[n], acc[m][n]);
    }
    __builtin_amdgcn_s_barrier();
  }

#pragma unroll
  for (int m = 0; m < 4; ++m)
#pragma unroll
    for (int n = 0; n < 2; ++n)
#pragma unroll
      for (int r = 0; r < 4; ++r) {
        const int row = bm + wr * 64 + m * 16 + fg * 4 + r;
        const int col = bn + wc * 32 + n * 16 + fr;
        Out[(size_t)row * 1024 + col] = acc[m][n][r];
      }
}

// ---------------------------------------------------------------------------
// Flash attention, causal, KV-split + XCD pinning (R24, unchanged).
// ---------------------------------------------------------------------------
__device__ __forceinline__ int SWZ(int row, int col) {
  return row * 64 + (col ^ ((row & 7) << 3));
}

__global__ __launch_bounds__(512, 2) void flash_attn(
    const __bf16* __restrict__ Q, const __bf16* __restrict__ K,
    const __bf16* __restrict__ Vt, __bf16* __restrict__ O) {
  __shared__ alignas(16) __bf16 Ks[2][2][64 * 64];  // [grp][buf] 32 KB
  __shared__ alignas(16) __bf16 Vs[2][2][64 * 64];  // 32 KB
  __shared__ alignas(16) __bf16 Ps[8][16 * 64];     // 16 KB (reused: merge acc)

  const int f  = blockIdx.x;            // 0..1023
  const int x  = f & 7, w = f >> 3;     // w 0..127
  const int qt = 31 - (w >> 2);         // longest first
  const int bh = x * 4 + (w & 3);
  const int b  = bh >> 4;
  const int h  = bh & 15;

  const int tid  = threadIdx.x;
  const int lane = tid & 63, wave = tid >> 6;
  const int grp = wave >> 2, wg = wave & 3;  // group / wave-in-group
  const int fr = lane & 15, fg = lane >> 4;

  const int len = qt + 1;
  const int h0  = (len + 1) >> 1;       // grp0 [0,h0), grp1 [h0,len)
  const int t0  = grp ? h0 : 0;
  const int tlast = grp ? len : h0;     // exclusive end of this grp's range

  const __bf16* Kh = K + (size_t)b * SEQ * D_MODEL + h * DKH;
  const __bf16* Vh = Vt + (size_t)(bh * DKH) * SEQ;

  auto stage = [&](int buf, int t) {
#pragma unroll
    for (int p = 0; p < 2; ++p) {
      const int row = p * 32 + wg * 8 + (lane >> 3);
      const int sg  = (lane & 7) ^ (row & 7);
      const __bf16* ks = Kh + (size_t)(t * KB + row) * D_MODEL + sg * 8;
      __builtin_amdgcn_global_load_lds((gas_u32)ks,
          (las_u32)(&Ks[grp][buf][(size_t)(p * 256 + wg * 64) * 8]), 16, 0, 0);
      const __bf16* vs = Vh + (size_t)row * SEQ + t * KB + sg * 8;
      __builtin_amdgcn_global_load_lds((gas_u32)vs,
          (las_u32)(&Vs[grp][buf][(size_t)(p * 256 + wg * 64) * 8]), 16, 0, 0);
    }
  };

  f32x4 acc[4];
#pragma unroll
  for (int n = 0; n < 4; ++n) acc[n] = (f32x4){0.f, 0.f, 0.f, 0.f};
  f32x4 l4 = (f32x4){0.f, 0.f, 0.f, 0.f};

  bf16x8 q0, q1;
  {
    const size_t qrow = (size_t)(b * SEQ + qt * QB + wg * 16 + fr) * D_MODEL + h * DKH;
    q0 = *(const bf16x8*)(Q + qrow + fg * 8);
    q1 = *(const bf16x8*)(Q + qrow + 32 + fg * 8);
  }

  const bf16x8 ones = {(__bf16)1.f, (__bf16)1.f, (__bf16)1.f, (__bf16)1.f,
                       (__bf16)1.f, (__bf16)1.f, (__bf16)1.f, (__bf16)1.f};

  auto step = [&](const int t, const int cur, __bf16* __restrict__ ps) {
    f32x4 s[4];
    __builtin_amdgcn_s_setprio(1);
#pragma unroll
    for (int kb = 0; kb < 4; ++kb) {
      f32x4 a = (f32x4){0.f, 0.f, 0.f, 0.f};
      bf16x8 kf0 = *(const bf16x8*)&Ks[grp][cur][SWZ(kb * 16 + fr, fg * 8)];
      bf16x8 kf1 = *(const bf16x8*)&Ks[grp][cur][SWZ(kb * 16 + fr, 32 + fg * 8)];
      a = MFMA16(kf0, q0, a);
      a = MFMA16(kf1, q1, a);
      s[kb] = a;
    }
    __builtin_amdgcn_s_setprio(0);

    if (t == qt) {  // causal mask, lane-local (diagonal KV tile)
      const int qin = wg * 16 + fr;
#pragma unroll
      for (int kb = 0; kb < 4; ++kb)
#pragma unroll
        for (int r = 0; r < 4; ++r)
          if (kb * 16 + fg * 4 + r > qin) s[kb][r] = -INFINITY;
    }

#pragma unroll
    for (int kb = 0; kb < 4; ++kb) {
      bf16x4 wv = {(__bf16)__builtin_amdgcn_exp2f(s[kb][0]),
                   (__bf16)__builtin_amdgcn_exp2f(s[kb][1]),
                   (__bf16)__builtin_amdgcn_exp2f(s[kb][2]),
                   (__bf16)__builtin_amdgcn_exp2f(s[kb][3])};
      *(bf16x4*)&ps[SWZ(fr, kb * 16 + fg * 4)] = wv;
    }

    __builtin_amdgcn_s_setprio(1);
#pragma unroll
    for (int k2 = 0; k2 < 2; ++k2) {
      bf16x8 pf = *(const bf16x8*)&ps[SWZ(fr, k2 * 32 + fg * 8)];
#pragma unroll
      for (int n = 0; n < 4; ++n) {
        bf16x8 vf = *(const bf16x8*)&Vs[grp][cur][SWZ(n * 16 + fr, k2 * 32 + fg * 8)];
        acc[n] = MFMA16(pf, vf, acc[n]);
      }
      l4 = MFMA16(pf, ones, l4);
    }
    __builtin_amdgcn_s_setprio(0);
  };

  stage(0, t0);
  asm volatile("s_waitcnt vmcnt(0)" ::: "memory");
  __syncthreads();

#pragma unroll 1
  for (int i = 0; i < h0; ++i) {
    const int t = t0 + i;
    const int cur = i & 1;

    if (t + 1 < tlast) stage(cur ^ 1, t + 1);  // latency hides under step
    if (t < tlast) step(t, cur, &Ps[wave][0]);

    asm volatile("s_waitcnt vmcnt(0)" ::: "memory");
    __syncthreads();
  }

  // ---- merge (m=0): O = (acc0 + acc1) / (l0 + l1) ----
  float* accb = (float*)&Ps[0][0];        // 4 waves x 16 x 64 f32 = 16 KB
  float* lb   = (float*)&Ks[0][0][0];     // 4 KB scratch (grp0 buf0, done)
  if (grp == 1) {
#pragma unroll
    for (int n = 0; n < 4; ++n)
#pragma unroll
      for (int r = 0; r < 4; ++r)
        accb[(wg * 16 + n * 4 + r) * 64 + lane] = acc[n][r];
#pragma unroll
    for (int r = 0; r < 4; ++r) lb[(wg * 4 + r) * 64 + lane] = l4[r];
  }
  __syncthreads();
  if (grp == 0) {
#pragma unroll
    for (int n = 0; n < 4; ++n)
#pragma unroll
      for (int r = 0; r < 4; ++r) acc[n][r] += accb[(wg * 16 + n * 4 + r) * 64 + lane];
#pragma unroll
    for (int r = 0; r < 4; ++r) l4[r] += lb[(wg * 4 + r) * 64 + lane];

    const size_t obase = (size_t)(b * SEQ + qt * QB + wg * 16) * D_MODEL + h * DKH;
#pragma unroll
    for (int n = 0; n < 4; ++n)
#pragma unroll
      for (int r = 0; r < 4; ++r) {
        const int row = fg * 4 + r;
        O[obase + (size_t)row * D_MODEL + n * 16 + fr] =
            (__bf16)(acc[n][r] / l4[r]);
      }
  }
}

// ---------------------------------------------------------------------------
extern "C" void kernel_launch(void* const* d_in, const int* in_sizes, int n_in,
                              void* d_out, int out_size, void* d_ws, size_t ws_size,
                              hipStream_t stream) {
  const float* q_src = (const float*)d_in[0];
  const float* k_src = (const float*)d_in[1];
  const float* v_src = (const float*)d_in[2];
  // d_in[3] = causal tril mask (fixed) -> applied analytically
  const float* Wq = (const float*)d_in[4];
  const float* Wk = (const float*)d_in[5];
  const float* Wv = (const float*)d_in[6];
  const float* Wo = (const float*)d_in[7];

  const size_t NE = (size_t)M_ROWS * D_MODEL;  // 4M elems
  const size_t NW = (size_t)D_MODEL * D_MODEL; // 1M elems
  __bf16* Xq  = (__bf16*)d_ws;
  __bf16* Xk  = Xq + NE;
  __bf16* Xv  = Xk + NE;
  __bf16* Wqb = Xv + NE;
  __bf16* Wkb = Wqb + NW;
  __bf16* Wvb = Wkb + NW;
  __bf16* Wob = Wvb + NW;
  __bf16* Q   = Wob + NW;
  __bf16* K   = Q + NE;
  __bf16* Vt  = K + NE;
  __bf16* A   = Xq;  // Xq consumed by proj_qkv before flash writes A

  CvtArgs ca;
  ca.src[0] = q_src; ca.dst[0] = Xq;  ca.n8[0] = (int)(NE / 8);
  ca.src[1] = k_src; ca.dst[1] = Xk;  ca.n8[1] = (int)(NE / 8);
  ca.src[2] = v_src; ca.dst[2] = Xv;  ca.n8[2] = (int)(NE / 8);
  ca.src[3] = Wq;    ca.dst[3] = Wqb; ca.n8[3] = (int)(NW / 8);  // x0.125*log2e
  ca.src[4] = Wk;    ca.dst[4] = Wkb; ca.n8[4] = (int)(NW / 8);
  ca.src[5] = Wv;    ca.dst[5] = Wvb; ca.n8[5] = (int)(NW / 8);
  ca.src[6] = Wo;    ca.dst[6] = Wob; ca.n8[6] = (int)(NW / 8);

  cvt_bf16<<<dim3((unsigned)(NE / 8 / 256), 1, 7), dim3(256), 0, stream>>>(ca);
  proj_qkv<<<dim3(768), dim3(256), 0, stream>>>(
      Xq, Xk, Xv, Wqb, Wkb, Wvb, Q, K, Vt);
  flash_attn<<<dim3(NT * BATCH * HEADS), dim3(512), 0, stream>>>(Q, K, Vt, A);
  proj_out<<<dim3(512), dim3(256), 0, stream>>>(A, Wob, (float*)d_out);
}

// Round 29
// 105.332 us; speedup vs baseline: 1.0299x; 1.0088x over previous
//
#include <hip/hip_runtime.h>
#include <hip/hip_bf16.h>

// MultiheadAttention: out = (softmax_causal((Xq Wq^T)(Xk Wk^T)^T / 8) (Xv Wv^T)) Wo^T
// B=2 S=2048 D=1024 H=16 dk=64. bf16 MFMA (16x16x32), fp32 accum.
// R29: proj_qkv 8 waves/block (512 thr, 2x4 grid, wave tile 64x32,
//      acc[4][2]=32 regs -> no R22 spill hazard; launch_bounds(512,4) caps
//      VGPR 128 >> ~75 working set). LDS 64KB -> 2 blocks/CU -> 4 waves/SIMD
//      (2x TLP, the one untested axis). vmcnt(4) steady. Others = R28.

typedef __attribute__((ext_vector_type(8))) __bf16 bf16x8;
typedef __attribute__((ext_vector_type(4))) __bf16 bf16x4;
typedef __attribute__((ext_vector_type(4))) float f32x4;

#define MFMA16(a, b, c) __builtin_amdgcn_mfma_f32_16x16x32_bf16((a), (b), (c), 0, 0, 0)

constexpr int D_MODEL = 1024;
constexpr int HEADS   = 16;
constexpr int DKH     = 64;
constexpr int BATCH   = 2;
constexpr int SEQ     = 2048;
constexpr int M_ROWS  = BATCH * SEQ;  // 4096
constexpr int QB = 64, KB = 64, NT = SEQ / QB;  // 32 q-tiles

typedef const unsigned int __attribute__((address_space(1)))* gas_u32;
typedef unsigned int __attribute__((address_space(3)))* las_u32;

// ---------------------------------------------------------------------------
// fp32 -> bf16 convert; seg 3 (Wq) pre-scaled by 0.125*log2(e) (exp2 softmax).
// Segs 0-5 granule-swizzled for the GEMM staging (rule #21).
// ---------------------------------------------------------------------------
struct CvtArgs {
  const float* src[7];
  __bf16* dst[7];
  int n8[7];
};

__global__ __launch_bounds__(256) void cvt_bf16(CvtArgs a) {
  const int z = blockIdx.z;
  const int i = blockIdx.x * 256 + threadIdx.x;
  if (i >= a.n8[z]) return;
  const float sc = (z == 3) ? 0.18033688011112042f : 1.0f;  // 0.125*log2e
  const float4* s = (const float4*)a.src[z] + (size_t)i * 2;
  float4 x = s[0], y = s[1];
  bf16x8 o = {(__bf16)(x.x * sc), (__bf16)(x.y * sc), (__bf16)(x.z * sc), (__bf16)(x.w * sc),
              (__bf16)(y.x * sc), (__bf16)(y.y * sc), (__bf16)(y.z * sc), (__bf16)(y.w * sc)};
  size_t oi = (size_t)i;
  if (z < 6) {
    const int row = i >> 7;  // 1024 elems = 128 granules per row
    oi = (size_t)((i & ~7) | ((i & 7) ^ (row & 7)));
  }
  *(bf16x8*)(a.dst[z] + oi * 8) = o;
}

// ---------------------------------------------------------------------------
// proj_qkv: 128x128 tile, 8 waves (2x4 grid, wave tile 64x32), dbuf,
// counted vmcnt(4). Grid 768 (3 full CU rounds), XCD-pinned A panels.
// ---------------------------------------------------------------------------
__global__ __launch_bounds__(512, 4) void proj_qkv(
    const __bf16* __restrict__ Xq, const __bf16* __restrict__ Xk,
    const __bf16* __restrict__ Xv, const __bf16* __restrict__ Wq,
    const __bf16* __restrict__ Wk, const __bf16* __restrict__ Wv,
    __bf16* __restrict__ Q, __bf16* __restrict__ K, __bf16* __restrict__ Vt) {
  __shared__ alignas(16) __bf16 As[2][128 * 64];  // 32 KB
  __shared__ alignas(16) __bf16 Bs[2][128 * 64];  // 32 KB

  const int f = blockIdx.x;
  const int x = f & 7, w = f >> 3;
  const int bz = w >> 5, rem = w & 31;
  const int by = x * 4 + (rem & 3);
  const int bx = rem >> 2;

  const __bf16* Ag; const __bf16* Bg;
  if (bz == 0)      { Ag = Xq; Bg = Wq; }
  else if (bz == 1) { Ag = Xk; Bg = Wk; }
  else              { Ag = Xv; Bg = Wv; }

  const int bm = by * 128, bn = bx * 128;
  const int tid = threadIdx.x, ln = tid & 63, wv = tid >> 6;  // wv 0..7
  const int wr = wv >> 2, wc = wv & 3;       // 2x4 wave grid, tile 64x32
  const int fr = ln & 15, fg = ln >> 4;

  // stage one 128x64 A-tile + B-tile (16 chunks of 1KB each; 2 chunks/wave
  // per operand) -> 4 global_load_lds per thread per tile.
  auto stage = [&](int buf, int t) {
    const int kt = t * 64;
#pragma unroll
    for (int i = 0; i < 2; ++i) {
      const int c = wv * 2 + i;            // 0..15
      const int byte = c * 1024 + ln * 16;
      const int row = byte >> 7;
      const int col = (byte & 127) >> 1;
      const __bf16* ga = Ag + (size_t)(bm + row) * 1024 + kt + col;
      __builtin_amdgcn_global_load_lds((gas_u32)ga, (las_u32)(&As[buf][c * 512]),
                                       16, 0, 0);
      const __bf16* gb = Bg + (size_t)(bn + row) * 1024 + kt + col;
      __builtin_amdgcn_global_load_lds((gas_u32)gb, (las_u32)(&Bs[buf][c * 512]),
                                       16, 0, 0);
    }
  };

  f32x4 acc[4][2];
#pragma unroll
  for (int m = 0; m < 4; ++m)
#pragma unroll
    for (int n = 0; n < 2; ++n) acc[m][n] = (f32x4){0.f, 0.f, 0.f, 0.f};

  stage(0, 0);

#pragma unroll 1
  for (int t = 0; t < 16; ++t) {
    const int cur = t & 1;
    // stage t+1 into buf cur^1 (readers finished at iter t-1's trailing
    // barrier); newest 4 outstanding = tile t+1 -> vmcnt(4) proves t landed.
    if (t + 1 < 16) {
      stage(cur ^ 1, t + 1);
      asm volatile("s_waitcnt vmcnt(4)" ::: "memory");
    } else {
      asm volatile("s_waitcnt vmcnt(0)" ::: "memory");
    }
    __builtin_amdgcn_s_barrier();

#pragma unroll
    for (int kk = 0; kk < 2; ++kk) {
      bf16x8 af[4], bfv[2];
#pragma unroll
      for (int m = 0; m < 4; ++m) {
        const int row = wr * 64 + m * 16 + fr;
        af[m] = *(const bf16x8*)&As[cur][row * 64 + (((kk * 4 + fg) ^ (row & 7)) << 3)];
      }
#pragma unroll
      for (int n = 0; n < 2; ++n) {
        const int row = wc * 32 + n * 16 + fr;
        bfv[n] = *(const bf16x8*)&Bs[cur][row * 64 + (((kk * 4 + fg) ^ (row & 7)) << 3)];
      }
      __builtin_amdgcn_s_setprio(1);
#pragma unroll
      for (int m = 0; m < 4; ++m)
#pragma unroll
        for (int n = 0; n < 2; ++n) acc[m][n] = MFMA16(af[m], bfv[n], acc[m][n]);
      __builtin_amdgcn_s_setprio(0);
    }
    __builtin_amdgcn_s_barrier();  // protect buf cur from next iter's stage
  }

  if (bz == 2) {
    // Vt[(b*1024 + col)][s]: per frag 4 contiguous s at fixed col
    const int b = bm >> 11;
#pragma unroll
    for (int m = 0; m < 4; ++m)
#pragma unroll
      for (int n = 0; n < 2; ++n) {
        const int col = bn + wc * 32 + n * 16 + fr;
        const int s0  = (bm + wr * 64 + m * 16 + fg * 4) & (SEQ - 1);
        bf16x4 o = {(__bf16)acc[m][n][0], (__bf16)acc[m][n][1],
                    (__bf16)acc[m][n][2], (__bf16)acc[m][n][3]};
        *(bf16x4*)(Vt + (((size_t)(b * 1024 + col)) << 11) + s0) = o;
      }
  } else {
    __bf16* C = (bz == 0) ? Q : K;
#pragma unroll
    for (int m = 0; m < 4; ++m)
#pragma unroll
      for (int n = 0; n < 2; ++n)
#pragma unroll
        for (int r = 0; r < 4; ++r) {
          const int row = bm + wr * 64 + m * 16 + fg * 4 + r;
          const int col = bn + wc * 32 + n * 16 + fr;
          C[(size_t)row * 1024 + col] = (__bf16)acc[m][n][r];
        }
  }
}

// ---------------------------------------------------------------------------
// proj_out: 128x64 tile, double-buffered, counted vmcnt(6), XCD-pinned map
// (R25, unchanged).
// ---------------------------------------------------------------------------
__global__ __launch_bounds__(256) void proj_out(const __bf16* __restrict__ Aattn,
                                                const __bf16* __restrict__ Wo,
                                                float* __restrict__ Out) {
  __shared__ alignas(16) __bf16 As[2][128 * 64];  // 32 KB
  __shared__ alignas(16) __bf16 Bs[2][64 * 64];   // 16 KB

  const int f = blockIdx.x;             // 0..511
  const int x = f & 7, w = f >> 3;
  const int by = x * 4 + (w & 3);       // 0..31
  const int bx = w >> 2;                // 0..15
  const int bm = by * 128, bn = bx * 64;

  const int tid = threadIdx.x, ln = tid & 63, wv = tid >> 6;
  const int wr = wv >> 1, wc = wv & 1;
  const int fr = ln & 15, fg = ln >> 4;

  auto stage = [&](int buf, int t) {
    const int kt = t * 64;
#pragma unroll
    for (int i = 0; i < 4; ++i) {  // A: 16 chunks of 1KB
      const int c = wv * 4 + i;
      const int byte = c * 1024 + ln * 16;
      const int row = byte >> 7;
      const int col = (byte & 127) >> 1;
      const __bf16* ga = Aattn + (size_t)(bm + row) * 1024 + kt + col;
      __builtin_amdgcn_global_load_lds((gas_u32)ga, (las_u32)(&As[buf][c * 512]),
                                       16, 0, 0);
    }
#pragma unroll
    for (int i = 0; i < 2; ++i) {  // B: 8 chunks of 1KB
      const int c = wv * 2 + i;
      const int byte = c * 1024 + ln * 16;
      const int row = byte >> 7;
      const int col = (byte & 127) >> 1;
      const __bf16* gb = Wo + (size_t)(bn + row) * 1024 + kt + col;
      __builtin_amdgcn_global_load_lds((gas_u32)gb, (las_u32)(&Bs[buf][c * 512]),
                                       16, 0, 0);
    }
  };

  f32x4 acc[4][2];
#pragma unroll
  for (int m = 0; m < 4; ++m)
#pragma unroll
    for (int n = 0; n < 2; ++n) acc[m][n] = (f32x4){0.f, 0.f, 0.f, 0.f};

  stage(0, 0);

#pragma unroll 1
  for (int t = 0; t < 16; ++t) {
    const int cur = t & 1;
    if (t + 1 < 16) {
      stage(cur ^ 1, t + 1);
      asm volatile("s_waitcnt vmcnt(6)" ::: "memory");  // tile t landed
    } else {
      asm volatile("s_waitcnt vmcnt(0)" ::: "memory");
    }
    __builtin_amdgcn_s_barrier();

#pragma unroll
    for (int kk = 0; kk < 2; ++kk) {
      const int kc = kk * 32 + fg * 8;
      bf16x8 af[4], bfv[2];
#pragma unroll
      for (int m = 0; m < 4; ++m)
        af[m] = *(const bf16x8*)&As[cur][(wr * 64 + m * 16 + fr) * 64 + kc];
#pragma unroll
      for (int n = 0; n < 2; ++n)
        bfv[n] = *(const bf16x8*)&Bs[cur][(wc * 32 + n * 16 + fr) * 64 + kc];
#pragma unroll
      for (int m = 0; m < 4; ++m)
#pragma unroll
        for (int n = 0; n < 2; ++n) acc[m][n] = MFMA16(af[m], bfv[n], acc[m][n]);
    }
    __builtin_amdgcn_s_barrier();
  }

#pragma unroll
  for (int m = 0; m < 4; ++m)
#pragma unroll
    for (int n = 0; n < 2; ++n)
#pragma unroll
      for (int r = 0; r < 4; ++r) {
        const int row = bm + wr * 64 + m * 16 + fg * 4 + r;
        const int col = bn + wc * 32 + n * 16 + fr;
        Out[(size_t)row * 1024 + col] = acc[m][n][r];
      }
}

// ---------------------------------------------------------------------------
// Flash attention, causal, KV-split + XCD pinning (R24, unchanged).
// ---------------------------------------------------------------------------
__device__ __forceinline__ int SWZ(int row, int col) {
  return row * 64 + (col ^ ((row & 7) << 3));
}

__global__ __launch_bounds__(512, 2) void flash_attn(
    const __bf16* __restrict__ Q, const __bf16* __restrict__ K,
    const __bf16* __restrict__ Vt, __bf16* __restrict__ O) {
  __shared__ alignas(16) __bf16 Ks[2][2][64 * 64];  // [grp][buf] 32 KB
  __shared__ alignas(16) __bf16 Vs[2][2][64 * 64];  // 32 KB
  __shared__ alignas(16) __bf16 Ps[8][16 * 64];     // 16 KB (reused: merge acc)

  const int f  = blockIdx.x;            // 0..1023
  const int x  = f & 7, w = f >> 3;     // w 0..127
  const int qt = 31 - (w >> 2);         // longest first
  const int bh = x * 4 + (w & 3);
  const int b  = bh >> 4;
  const int h  = bh & 15;

  const int tid  = threadIdx.x;
  const int lane = tid & 63, wave = tid >> 6;
  const int grp = wave >> 2, wg = wave & 3;  // group / wave-in-group
  const int fr = lane & 15, fg = lane >> 4;

  const int len = qt + 1;
  const int h0  = (len + 1) >> 1;       // grp0 [0,h0), grp1 [h0,len)
  const int t0  = grp ? h0 : 0;
  const int tlast = grp ? len : h0;     // exclusive end of this grp's range

  const __bf16* Kh = K + (size_t)b * SEQ * D_MODEL + h * DKH;
  const __bf16* Vh = Vt + (size_t)(bh * DKH) * SEQ;

  auto stage = [&](int buf, int t) {
#pragma unroll
    for (int p = 0; p < 2; ++p) {
      const int row = p * 32 + wg * 8 + (lane >> 3);
      const int sg  = (lane & 7) ^ (row & 7);
      const __bf16* ks = Kh + (size_t)(t * KB + row) * D_MODEL + sg * 8;
      __builtin_amdgcn_global_load_lds((gas_u32)ks,
          (las_u32)(&Ks[grp][buf][(size_t)(p * 256 + wg * 64) * 8]), 16, 0, 0);
      const __bf16* vs = Vh + (size_t)row * SEQ + t * KB + sg * 8;
      __builtin_amdgcn_global_load_lds((gas_u32)vs,
          (las_u32)(&Vs[grp][buf][(size_t)(p * 256 + wg * 64) * 8]), 16, 0, 0);
    }
  };

  f32x4 acc[4];
#pragma unroll
  for (int n = 0; n < 4; ++n) acc[n] = (f32x4){0.f, 0.f, 0.f, 0.f};
  f32x4 l4 = (f32x4){0.f, 0.f, 0.f, 0.f};

  bf16x8 q0, q1;
  {
    const size_t qrow = (size_t)(b * SEQ + qt * QB + wg * 16 + fr) * D_MODEL + h * DKH;
    q0 = *(const bf16x8*)(Q + qrow + fg * 8);
    q1 = *(const bf16x8*)(Q + qrow + 32 + fg * 8);
  }

  const bf16x8 ones = {(__bf16)1.f, (__bf16)1.f, (__bf16)1.f, (__bf16)1.f,
                       (__bf16)1.f, (__bf16)1.f, (__bf16)1.f, (__bf16)1.f};

  auto step = [&](const int t, const int cur, __bf16* __restrict__ ps) {
    f32x4 s[4];
    __builtin_amdgcn_s_setprio(1);
#pragma unroll
    for (int kb = 0; kb < 4; ++kb) {
      f32x4 a = (f32x4){0.f, 0.f, 0.f, 0.f};
      bf16x8 kf0 = *(const bf16x8*)&Ks[grp][cur][SWZ(kb * 16 + fr, fg * 8)];
      bf16x8 kf1 = *(const bf16x8*)&Ks[grp][cur][SWZ(kb * 16 + fr, 32 + fg * 8)];
      a = MFMA16(kf0, q0, a);
      a = MFMA16(kf1, q1, a);
      s[kb] = a;
    }
    __builtin_amdgcn_s_setprio(0);

    if (t == qt) {  // causal mask, lane-local (diagonal KV tile)
      const int qin = wg * 16 + fr;
#pragma unroll
      for (int kb = 0; kb < 4; ++kb)
#pragma unroll
        for (int r = 0; r < 4; ++r)
          if (kb * 16 + fg * 4 + r > qin) s[kb][r] = -INFINITY;
    }

#pragma unroll
    for (int kb = 0; kb < 4; ++kb) {
      bf16x4 wv = {(__bf16)__builtin_amdgcn_exp2f(s[kb][0]),
                   (__bf16)__builtin_amdgcn_exp2f(s[kb][1]),
                   (__bf16)__builtin_amdgcn_exp2f(s[kb][2]),
                   (__bf16)__builtin_amdgcn_exp2f(s[kb][3])};
      *(bf16x4*)&ps[SWZ(fr, kb * 16 + fg * 4)] = wv;
    }

    __builtin_amdgcn_s_setprio(1);
#pragma unroll
    for (int k2 = 0; k2 < 2; ++k2) {
      bf16x8 pf = *(const bf16x8*)&ps[SWZ(fr, k2 * 32 + fg * 8)];
#pragma unroll
      for (int n = 0; n < 4; ++n) {
        bf16x8 vf = *(const bf16x8*)&Vs[grp][cur][SWZ(n * 16 + fr, k2 * 32 + fg * 8)];
        acc[n] = MFMA16(pf, vf, acc[n]);
      }
      l4 = MFMA16(pf, ones, l4);
    }
    __builtin_amdgcn_s_setprio(0);
  };

  stage(0, t0);
  asm volatile("s_waitcnt vmcnt(0)" ::: "memory");
  __syncthreads();

#pragma unroll 1
  for (int i = 0; i < h0; ++i) {
    const int t = t0 + i;
    const int cur = i & 1;

    if (t + 1 < tlast) stage(cur ^ 1, t + 1);  // latency hides under step
    if (t < tlast) step(t, cur, &Ps[wave][0]);

    asm volatile("s_waitcnt vmcnt(0)" ::: "memory");
    __syncthreads();
  }

  // ---- merge (m=0): O = (acc0 + acc1) / (l0 + l1) ----
  float* accb = (float*)&Ps[0][0];        // 4 waves x 16 x 64 f32 = 16 KB
  float* lb   = (float*)&Ks[0][0][0];     // 4 KB scratch (grp0 buf0, done)
  if (grp == 1) {
#pragma unroll
    for (int n = 0; n < 4; ++n)
#pragma unroll
      for (int r = 0; r < 4; ++r)
        accb[(wg * 16 + n * 4 + r) * 64 + lane] = acc[n][r];
#pragma unroll
    for (int r = 0; r < 4; ++r) lb[(wg * 4 + r) * 64 + lane] = l4[r];
  }
  __syncthreads();
  if (grp == 0) {
#pragma unroll
    for (int n = 0; n < 4; ++n)
#pragma unroll
      for (int r = 0; r < 4; ++r) acc[n][r] += accb[(wg * 16 + n * 4 + r) * 64 + lane];
#pragma unroll
    for (int r = 0; r < 4; ++r) l4[r] += lb[(wg * 4 + r) * 64 + lane];

    const size_t obase = (size_t)(b * SEQ + qt * QB + wg * 16) * D_MODEL + h * DKH;
#pragma unroll
    for (int n = 0; n < 4; ++n)
#pragma unroll
      for (int r = 0; r < 4; ++r) {
        const int row = fg * 4 + r;
        O[obase + (size_t)row * D_MODEL + n * 16 + fr] =
            (__bf16)(acc[n][r] / l4[r]);
      }
  }
}

// ---------------------------------------------------------------------------
extern "C" void kernel_launch(void* const* d_in, const int* in_sizes, int n_in,
                              void* d_out, int out_size, void* d_ws, size_t ws_size,
                              hipStream_t stream) {
  const float* q_src = (const float*)d_in[0];
  const float* k_src = (const float*)d_in[1];
  const float* v_src = (const float*)d_in[2];
  // d_in[3] = causal tril mask (fixed) -> applied analytically
  const float* Wq = (const float*)d_in[4];
  const float* Wk = (const float*)d_in[5];
  const float* Wv = (const float*)d_in[6];
  const float* Wo = (const float*)d_in[7];

  const size_t NE = (size_t)M_ROWS * D_MODEL;  // 4M elems
  const size_t NW = (size_t)D_MODEL * D_MODEL; // 1M elems
  __bf16* Xq  = (__bf16*)d_ws;
  __bf16* Xk  = Xq + NE;
  __bf16* Xv  = Xk + NE;
  __bf16* Wqb = Xv + NE;
  __bf16* Wkb = Wqb + NW;
  __bf16* Wvb = Wkb + NW;
  __bf16* Wob = Wvb + NW;
  __bf16* Q   = Wob + NW;
  __bf16* K   = Q + NE;
  __bf16* Vt  = K + NE;
  __bf16* A   = Xq;  // Xq consumed by proj_qkv before flash writes A

  CvtArgs ca;
  ca.src[0] = q_src; ca.dst[0] = Xq;  ca.n8[0] = (int)(NE / 8);
  ca.src[1] = k_src; ca.dst[1] = Xk;  ca.n8[1] = (int)(NE / 8);
  ca.src[2] = v_src; ca.dst[2] = Xv;  ca.n8[2] = (int)(NE / 8);
  ca.src[3] = Wq;    ca.dst[3] = Wqb; ca.n8[3] = (int)(NW / 8);  // x0.125*log2e
  ca.src[4] = Wk;    ca.dst[4] = Wkb; ca.n8[4] = (int)(NW / 8);
  ca.src[5] = Wv;    ca.dst[5] = Wvb; ca.n8[5] = (int)(NW / 8);
  ca.src[6] = Wo;    ca.dst[6] = Wob; ca.n8[6] = (int)(NW / 8);

  cvt_bf16<<<dim3((unsigned)(NE / 8 / 256), 1, 7), dim3(256), 0, stream>>>(ca);
  proj_qkv<<<dim3(768), dim3(512), 0, stream>>>(
      Xq, Xk, Xv, Wqb, Wkb, Wvb, Q, K, Vt);
  flash_attn<<<dim3(NT * BATCH * HEADS), dim3(512), 0, stream>>>(Q, K, Vt, A);
  proj_out<<<dim3(512), dim3(256), 0, stream>>>(A, Wob, (float*)d_out);
}